// Round 2
// baseline (63794.330 us; speedup 1.0000x reference)
//
#include <hip/hip_runtime.h>
#include <hip/hip_cooperative_groups.h>
#include <type_traits>

namespace cg = cooperative_groups;

typedef short v8s __attribute__((ext_vector_type(8)));
typedef float f32x4 __attribute__((ext_vector_type(4)));
typedef unsigned short u16;

static constexpr int kB = 64;    // batch
static constexpr int kH = 1024;  // hidden
static constexpr int kD = 128;   // input dim
static constexpr int kL = 3;     // layers
static constexpr int NBLK = 128; // persistent blocks: 64 slices x 2 m-pairs

__device__ __forceinline__ u16 f2b(float f) {
  union { float f; unsigned u; } v; v.f = f;
  unsigned r = v.u + 0x7fffu + ((v.u >> 16) & 1u);
  return (u16)(r >> 16);
}

__device__ __forceinline__ float sigm(float x) { return 1.f / (1.f + expf(-x)); }

struct Params {
  const float *x, *h0, *c0;
  const float *Wi0, *Wh0, *bi0, *bh0;
  const float *Wi1, *Wh1, *bi1, *bh1;
  const float *Wi2, *Wh2, *bi2, *bh2;
  const float *Wfc, *bfc;
  float *out;
  u16 *wb0i, *wb0h, *wb1i, *wb1h, *wb2i, *wb2h, *wbfc;
  u16 *xb, *hA, *hB, *curx;
  float *b0, *b1, *b2, *bfcs;
  int P, T;
};

// ---------------- init: fp32 -> bf16 conversions, bias sums, state init ----
__global__ void init_kernel(Params p) {
  long gid = (long)blockIdx.x * blockDim.x + threadIdx.x;
  long stride = (long)gridDim.x * blockDim.x;
  const long nw0i = 4096L * kD, nwh = 4096L * kH, nfc = (long)kD * kH;
  for (long i = gid; i < nw0i; i += stride) p.wb0i[i] = f2b(p.Wi0[i]);
  for (long i = gid; i < nwh; i += stride) {
    p.wb0h[i] = f2b(p.Wh0[i]);
    p.wb1i[i] = f2b(p.Wi1[i]);
    p.wb1h[i] = f2b(p.Wh1[i]);
    p.wb2i[i] = f2b(p.Wi2[i]);
    p.wb2h[i] = f2b(p.Wh2[i]);
  }
  for (long i = gid; i < nfc; i += stride) p.wbfc[i] = f2b(p.Wfc[i]);
  for (long i = gid; i < 4096; i += stride) {
    p.b0[i] = p.bi0[i] + p.bh0[i];
    p.b1[i] = p.bi1[i] + p.bh1[i];
    p.b2[i] = p.bi2[i] + p.bh2[i];
  }
  for (long i = gid; i < kD; i += stride) p.bfcs[i] = p.bfc[i];
  long nx = (long)p.P * kB * kD;
  for (long i = gid; i < nx; i += stride) {
    p.xb[i] = f2b(p.x[i]);
    p.out[i] = p.x[i];  // teacher-forced rows are exact copies
  }
  long nh = (long)kL * kB * kH;
  for (long i = gid; i < nh; i += stride) p.hA[i] = f2b(p.h0[i]);
}

// Interleaved x-part / h-part K-loops: 4 independent MFMA chains, depth 32.
// A-frag: row = lane&15 (batch), k = (lane>>4)*8 + j, row-major activations.
// B-frag: col = lane&15 -> W row (X*W^T), k contiguous, row-major weights.
template <int KIN>
__device__ __forceinline__ void layer_mm(
    f32x4& aX0, f32x4& aX1, f32x4& aH0, f32x4& aH1,
    const u16* __restrict__ xi0, const u16* __restrict__ xi1,
    const u16* __restrict__ hi0, const u16* __restrict__ hi1,
    const u16* __restrict__ wi, const u16* __restrict__ wh) {
  constexpr int XS = KIN / 32;  // x-part k-steps (4 for l0, 32 for l1/l2)
#pragma unroll 8
  for (int k = 0; k < 32; ++k) {
    v8s bh = *(const v8s*)(wh + k * 32);
    v8s a0 = *(const v8s*)(hi0 + k * 32);
    v8s a1 = *(const v8s*)(hi1 + k * 32);
    aH0 = __builtin_amdgcn_mfma_f32_16x16x32_bf16(a0, bh, aH0, 0, 0, 0);
    aH1 = __builtin_amdgcn_mfma_f32_16x16x32_bf16(a1, bh, aH1, 0, 0, 0);
    if (k < XS) {
      v8s bx = *(const v8s*)(wi + k * 32);
      v8s x0 = *(const v8s*)(xi0 + k * 32);
      v8s x1 = *(const v8s*)(xi1 + k * 32);
      aX0 = __builtin_amdgcn_mfma_f32_16x16x32_bf16(x0, bx, aX0, 0, 0, 0);
      aX1 = __builtin_amdgcn_mfma_f32_16x16x32_bf16(x1, bx, aX1, 0, 0, 0);
    }
  }
}

// ---------------- persistent cooperative RNN loop -------------------------
// 128 blocks: slice = bid&63 (16 hidden units), m-pair = bid>>6 (32 batch).
// Same-slice pair {s, s+64} -> same XCD under bid%8 round-robin (L2 reuse).
__global__ void __launch_bounds__(256) rnn_kernel(Params p) {
  cg::grid_group grid = cg::this_grid();
  const int tid = threadIdx.x, bid = blockIdx.x;
  const int lane = tid & 63, g = tid >> 6;  // wave = gate (i,f,g,o)
  const int colc = lane & 15, kq = lane >> 4;
  const int slice = bid & 63, mp = bid >> 6;
  const int h_base = slice * 16, b_base = mp * 32;
  const int w_row = g * kH + h_base + colc;  // weight row = gate output col
  // epilogue map: thread -> 2 (batch, hidden) cells per layer
  const int eh = h_base + (tid & 15);
  const int eb0 = b_base + (tid >> 4), eb1 = eb0 + 16;
  const int aoff = kq * 8;
  __shared__ float lg[4][32][17];
  const int T = p.T, P = p.P;

  float cr[kL][2];
#pragma unroll
  for (int l = 0; l < kL; ++l) {
    cr[l][0] = p.c0[(long)l * kB * kH + (long)eb0 * kH + eh];
    cr[l][1] = p.c0[(long)l * kB * kH + (long)eb1 * kH + eh];
  }

  auto stage = [&](auto kinc, const u16* Xi, const u16* Hi, const u16* Wi,
                   const u16* Wh, const float* bias, float* c2, u16* hOut) {
    constexpr int KIN = decltype(kinc)::value;
    f32x4 aX0 = {0.f, 0.f, 0.f, 0.f}, aX1 = aX0, aH0 = aX0, aH1 = aX0;
    layer_mm<KIN>(aX0, aX1, aH0, aH1,
                  Xi + (long)(b_base + colc) * KIN + aoff,
                  Xi + (long)(b_base + 16 + colc) * KIN + aoff,
                  Hi + (long)(b_base + colc) * kH + aoff,
                  Hi + (long)(b_base + 16 + colc) * kH + aoff,
                  Wi + (long)w_row * KIN + aoff, Wh + (long)w_row * kH + aoff);
    float bv = bias[w_row];
#pragma unroll
    for (int r = 0; r < 4; ++r) {  // D: col=lane&15 (n), row=kq*4+r (m)
      lg[g][kq * 4 + r][colc] = aX0[r] + aH0[r] + bv;
      lg[g][16 + kq * 4 + r][colc] = aX1[r] + aH1[r] + bv;
    }
    __syncthreads();
    {
      const int r0 = tid >> 4, cc = tid & 15;
      float iv = lg[0][r0][cc], fv = lg[1][r0][cc];
      float gv = lg[2][r0][cc], ov = lg[3][r0][cc];
      float cn = sigm(fv) * c2[0] + sigm(iv) * tanhf(gv);
      c2[0] = cn;
      hOut[(long)eb0 * kH + eh] = f2b(sigm(ov) * tanhf(cn));
      iv = lg[0][r0 + 16][cc]; fv = lg[1][r0 + 16][cc];
      gv = lg[2][r0 + 16][cc]; ov = lg[3][r0 + 16][cc];
      cn = sigm(fv) * c2[1] + sigm(iv) * tanhf(gv);
      c2[1] = cn;
      hOut[(long)eb1 * kH + eh] = f2b(sigm(ov) * tanhf(cn));
    }
    grid.sync();
  };

  for (int t = 0; t < T - 1; ++t) {
    const u16* hOld = (t & 1) ? p.hB : p.hA;
    u16* hNew = (t & 1) ? p.hA : p.hB;
    const u16* xin = (t < P) ? (p.xb + (long)t * (kB * kD)) : p.curx;

    stage(std::integral_constant<int, kD>{}, xin, hOld, p.wb0i, p.wb0h, p.b0,
          &cr[0][0], hNew);
    stage(std::integral_constant<int, kH>{}, hNew, hOld + (long)kB * kH,
          p.wb1i, p.wb1h, p.b1, &cr[1][0], hNew + (long)kB * kH);
    stage(std::integral_constant<int, kH>{}, hNew + (long)kB * kH,
          hOld + 2L * kB * kH, p.wb2i, p.wb2h, p.b2, &cr[2][0],
          hNew + 2L * kB * kH);

    if (t >= P - 1) {  // FC feedback only needed once generation starts
      if (bid < 8) {   // n-tile = bid (16 of 128 out dims), wave = m-tile
        f32x4 u0 = {0.f, 0.f, 0.f, 0.f}, u1 = u0;
        const u16* ap = hNew + 2L * kB * kH + (long)(g * 16 + colc) * kH + aoff;
        const u16* bp = p.wbfc + (long)(bid * 16 + colc) * kH + aoff;
#pragma unroll 8
        for (int k = 0; k < 16; ++k) {
          v8s a0 = *(const v8s*)(ap + k * 32);
          v8s b0 = *(const v8s*)(bp + k * 32);
          v8s a1 = *(const v8s*)(ap + 512 + k * 32);
          v8s b1 = *(const v8s*)(bp + 512 + k * 32);
          u0 = __builtin_amdgcn_mfma_f32_16x16x32_bf16(a0, b0, u0, 0, 0, 0);
          u1 = __builtin_amdgcn_mfma_f32_16x16x32_bf16(a1, b1, u1, 0, 0, 0);
        }
        float bv = p.bfcs[bid * 16 + colc];
#pragma unroll
        for (int r = 0; r < 4; ++r) {
          float val = sigm(u0[r] + u1[r] + bv);
          int bb = g * 16 + kq * 4 + r, d = bid * 16 + colc;
          p.out[(long)(t + 1) * (kB * kD) + (long)bb * kD + d] = val;
          p.curx[(long)bb * kD + d] = f2b(val);
        }
      }
      grid.sync();
    }
  }
}

extern "C" void kernel_launch(void* const* d_in, const int* in_sizes, int n_in,
                              void* d_out, int out_size, void* d_ws, size_t ws_size,
                              hipStream_t stream) {
  Params p;
  p.x   = (const float*)d_in[0];
  p.h0  = (const float*)d_in[1];
  p.c0  = (const float*)d_in[2];
  p.Wi0 = (const float*)d_in[3];
  p.Wh0 = (const float*)d_in[4];
  p.bi0 = (const float*)d_in[5];
  p.bh0 = (const float*)d_in[6];
  p.Wi1 = (const float*)d_in[7];
  p.Wh1 = (const float*)d_in[8];
  p.bi1 = (const float*)d_in[9];
  p.bh1 = (const float*)d_in[10];
  p.Wi2 = (const float*)d_in[11];
  p.Wh2 = (const float*)d_in[12];
  p.bi2 = (const float*)d_in[13];
  p.bh2 = (const float*)d_in[14];
  p.Wfc = (const float*)d_in[15];
  p.bfc = (const float*)d_in[16];
  p.out = (float*)d_out;
  p.P = in_sizes[0] / (kB * kD);
  p.T = out_size / (kB * kD);

  char* w = (char*)d_ws;
  auto alloc = [&](size_t bytes) {
    char* r = w;
    w += (bytes + 255) & ~(size_t)255;
    return r;
  };
  p.wb0i = (u16*)alloc(4096L * kD * 2);
  p.wb0h = (u16*)alloc(4096L * kH * 2);
  p.wb1i = (u16*)alloc(4096L * kH * 2);
  p.wb1h = (u16*)alloc(4096L * kH * 2);
  p.wb2i = (u16*)alloc(4096L * kH * 2);
  p.wb2h = (u16*)alloc(4096L * kH * 2);
  p.wbfc = (u16*)alloc((long)kD * kH * 2);
  p.xb   = (u16*)alloc((long)p.P * kB * kD * 2);
  p.hA   = (u16*)alloc((long)kL * kB * kH * 2);
  p.hB   = (u16*)alloc((long)kL * kB * kH * 2);
  p.curx = (u16*)alloc((long)kB * kD * 2);
  p.b0   = (float*)alloc(4096 * 4);
  p.b1   = (float*)alloc(4096 * 4);
  p.b2   = (float*)alloc(4096 * 4);
  p.bfcs = (float*)alloc(kD * 4);

  hipLaunchKernelGGL(init_kernel, dim3(512), dim3(256), 0, stream, p);
  void* args[] = { &p };
  hipLaunchCooperativeKernel((const void*)rnn_kernel, dim3(NBLK), dim3(256),
                             args, 0, stream);
}

// Round 5
// 47806.378 us; speedup vs baseline: 1.3344x; 1.3344x over previous
//
#include <hip/hip_runtime.h>
#include <hip/hip_cooperative_groups.h>

namespace cg = cooperative_groups;

typedef short v8s __attribute__((ext_vector_type(8)));
typedef float f32x4 __attribute__((ext_vector_type(4)));
typedef unsigned short u16;

static constexpr int kB = 64;    // batch
static constexpr int kH = 1024;  // hidden
static constexpr int kD = 128;   // input dim
static constexpr int kL = 3;     // layers
static constexpr int NBLK = 128; // proven cooperative grid size (round 2)
static constexpr int NTHR = 512; // 8 waves -> 8-way K-split, low VGPR/wave

__device__ __forceinline__ u16 f2b(float f) {
  union { float f; unsigned u; } v; v.f = f;
  unsigned r = v.u + 0x7fffu + ((v.u >> 16) & 1u);
  return (u16)(r >> 16);
}

__device__ __forceinline__ float sigm(float x) { return 1.f / (1.f + expf(-x)); }

struct Params {
  const float *x, *h0, *c0;
  const float *Wi0, *Wh0, *bi0, *bh0;
  const float *Wi1, *Wh1, *bi1, *bh1;
  const float *Wi2, *Wh2, *bi2, *bh2;
  const float *Wfc, *bfc;
  float *out;
  u16 *wb0i, *wb0h, *wb1i, *wb1h, *wb2i, *wb2h, *wbfc;
  u16 *xb, *hA, *hB, *curx;
  float *b0, *b1, *b2, *bfcs;
  int P, T;
};

// ---------------- init: fp32 -> bf16 conversions, bias sums, state init ----
__global__ void init_kernel(Params p) {
  long gid = (long)blockIdx.x * blockDim.x + threadIdx.x;
  long stride = (long)gridDim.x * blockDim.x;
  const long nw0i = 4096L * kD, nwh = 4096L * kH, nfc = (long)kD * kH;
  for (long i = gid; i < nw0i; i += stride) p.wb0i[i] = f2b(p.Wi0[i]);
  for (long i = gid; i < nwh; i += stride) {
    p.wb0h[i] = f2b(p.Wh0[i]);
    p.wb1i[i] = f2b(p.Wi1[i]);
    p.wb1h[i] = f2b(p.Wh1[i]);
    p.wb2i[i] = f2b(p.Wi2[i]);
    p.wb2h[i] = f2b(p.Wh2[i]);
  }
  for (long i = gid; i < nfc; i += stride) p.wbfc[i] = f2b(p.Wfc[i]);
  for (long i = gid; i < 4096; i += stride) {
    p.b0[i] = p.bi0[i] + p.bh0[i];
    p.b1[i] = p.bi1[i] + p.bh1[i];
    p.b2[i] = p.bi2[i] + p.bh2[i];
  }
  for (long i = gid; i < kD; i += stride) p.bfcs[i] = p.bfc[i];
  long nx = (long)p.P * kB * kD;
  for (long i = gid; i < nx; i += stride) {
    p.xb[i] = f2b(p.x[i]);
    p.out[i] = p.x[i];  // teacher-forced rows are exact copies
  }
  long nh = (long)kL * kB * kH;
  for (long i = gid; i < nh; i += stride) p.hA[i] = f2b(p.h0[i]);
}

// ---------------- persistent RNN: weights live in VGPRs, 8-way K-split ----
// 128 blocks x 512 thr. Block owns 8 hidden units [8b,8b+8) x 4 gates = 32
// gate-rows/layer as TWO n-tiles: tile j = gates {2j,2j+1}; col c -> gate
// 2j+(c>>3), unit c&7. Wave w (0..7) owns 1/8 of K; partials sum via LDS.
// MFMA 16x16x32: A row=lane&15(m), k=(lane>>4)*8+j; D col=lane&15, row=kq*4+r.
__global__ void __launch_bounds__(NTHR) rnn_kernel(Params p) {
  cg::grid_group grid = cg::this_grid();
  const int tid = threadIdx.x, bid = blockIdx.x;
  const int lane = tid & 63, w = tid >> 6;  // 8 waves
  const int colc = lane & 15, kq = lane >> 4;
  const int aoff = kq * 8;
  const int u7 = colc & 7, gh = colc >> 3;
  const long wr0 = (long)gh * kH + bid * 8 + u7;        // gate-rows 0/1 tile
  const long wr1 = (long)(2 + gh) * kH + bid * 8 + u7;  // gate-rows 2/3 tile

  // ---- one-time weight preload: 42 tiles = 168 VGPRs/wave ----
  // l0: 36 k-tiles over concat [x:4 | h:32]; wave w gets 5 (w<4) or 4 tiles.
  const int cnt0 = (w < 4) ? 5 : 4;
  const int off0 = (w < 4) ? w * 5 : 20 + (w - 4) * 4;
  v8s w0[2][5], w1[2][8], w2[2][8];
#pragma unroll
  for (int i = 0; i < 5; ++i)
    if (i < cnt0) {
      int gt = off0 + i;
      if (gt < 4) {
        w0[0][i] = *(const v8s*)(p.wb0i + wr0 * kD + gt * 32 + aoff);
        w0[1][i] = *(const v8s*)(p.wb0i + wr1 * kD + gt * 32 + aoff);
      } else {
        w0[0][i] = *(const v8s*)(p.wb0h + wr0 * kH + (gt - 4) * 32 + aoff);
        w0[1][i] = *(const v8s*)(p.wb0h + wr1 * kH + (gt - 4) * 32 + aoff);
      }
    }
  // l1/l2: 64 k-tiles over concat [x:32 | h:32]; waves 0-3 x-part, 4-7 h-part.
#pragma unroll
  for (int i = 0; i < 8; ++i) {
    int gt = w * 8 + i;
    const u16* s1 = (gt < 32) ? p.wb1i : p.wb1h;
    const u16* s2 = (gt < 32) ? p.wb2i : p.wb2h;
    int k = (gt & 31) * 32 + aoff;
    w1[0][i] = *(const v8s*)(s1 + wr0 * kH + k);
    w1[1][i] = *(const v8s*)(s1 + wr1 * kH + k);
    w2[0][i] = *(const v8s*)(s2 + wr0 * kH + k);
    w2[1][i] = *(const v8s*)(s2 + wr1 * kH + k);
  }

  // ---- per-thread cell state: 1 (batch, unit) cell per layer ----
  const int em = tid >> 3, eu = tid & 7;
  const int ehid = bid * 8 + eu;
  float cst[kL], brg[kL][4];
#pragma unroll
  for (int l = 0; l < kL; ++l)
    cst[l] = p.c0[(long)l * kB * kH + (long)em * kH + ehid];
  {
    const float* bp[3] = {p.b0, p.b1, p.b2};
#pragma unroll
    for (int l = 0; l < 3; ++l)
#pragma unroll
      for (int gg = 0; gg < 4; ++gg) brg[l][gg] = bp[l][gg * kH + ehid];
  }

  __shared__ float lg[8][64][18];  // stride 18: <=2-way bank aliasing (free)
  const int T = p.T, P = p.P;
  const f32x4 z4 = {0.f, 0.f, 0.f, 0.f};

  auto epilogue = [&](int l, f32x4(&acc)[2][4], u16* hOut) {
    float pre[4];
    // phase 0: n-tile 0 -> gates 0 (i), 1 (f)
#pragma unroll
    for (int mt = 0; mt < 4; ++mt)
#pragma unroll
      for (int r = 0; r < 4; ++r) lg[w][mt * 16 + kq * 4 + r][colc] = acc[0][mt][r];
    __syncthreads();
    {
      float s0 = 0.f, s1 = 0.f;
#pragma unroll
      for (int ww = 0; ww < 8; ++ww) {
        s0 += lg[ww][em][eu];
        s1 += lg[ww][em][8 + eu];
      }
      pre[0] = s0;
      pre[1] = s1;
    }
    __syncthreads();  // all phase-0 reads done before phase-1 overwrites
    // phase 1: n-tile 1 -> gates 2 (g), 3 (o)
#pragma unroll
    for (int mt = 0; mt < 4; ++mt)
#pragma unroll
      for (int r = 0; r < 4; ++r) lg[w][mt * 16 + kq * 4 + r][colc] = acc[1][mt][r];
    __syncthreads();
    {
      float s0 = 0.f, s1 = 0.f;
#pragma unroll
      for (int ww = 0; ww < 8; ++ww) {
        s0 += lg[ww][em][eu];
        s1 += lg[ww][em][8 + eu];
      }
      pre[2] = s0;
      pre[3] = s1;
    }
    float iv = pre[0] + brg[l][0], fv = pre[1] + brg[l][1];
    float gv = pre[2] + brg[l][2], ov = pre[3] + brg[l][3];
    float cn = sigm(fv) * cst[l] + sigm(iv) * tanhf(gv);
    cst[l] = cn;
    hOut[(long)em * kH + ehid] = f2b(sigm(ov) * tanhf(cn));
    // lg reused next layer only after the following grid.sync (block barrier)
  };

  for (int t = 0; t < T - 1; ++t) {
    const u16* hOld = (t & 1) ? p.hB : p.hA;
    u16* hNew = (t & 1) ? p.hA : p.hB;
    const u16* xin = (t < P) ? (p.xb + (long)t * kB * kD) : p.curx;

    // ===== layer 0 =====
    {
      f32x4 acc[2][4] = {z4, z4, z4, z4, z4, z4, z4, z4};
#pragma unroll
      for (int i = 0; i < 5; ++i)
        if (i < cnt0) {
          int gt = off0 + i;
          const u16* Ab;
          int stride, k;
          if (gt < 4) { Ab = xin;  stride = kD; k = gt * 32 + aoff; }
          else        { Ab = hOld; stride = kH; k = (gt - 4) * 32 + aoff; }
#pragma unroll
          for (int mt = 0; mt < 4; ++mt) {
            v8s a = *(const v8s*)(Ab + (long)(mt * 16 + colc) * stride + k);
            acc[0][mt] = __builtin_amdgcn_mfma_f32_16x16x32_bf16(a, w0[0][i], acc[0][mt], 0, 0, 0);
            acc[1][mt] = __builtin_amdgcn_mfma_f32_16x16x32_bf16(a, w0[1][i], acc[1][mt], 0, 0, 0);
          }
        }
      epilogue(0, acc, hNew);
    }
    grid.sync();

    // ===== layer 1 (x-part = h_l0 new, h-part = h_l1 old) =====
    {
      f32x4 acc[2][4] = {z4, z4, z4, z4, z4, z4, z4, z4};
      const u16* Ax = hNew;
      const u16* Ah = hOld + (long)kB * kH;
#pragma unroll
      for (int i = 0; i < 8; ++i) {
        int gt = w * 8 + i;
        const u16* Ab = (gt < 32) ? Ax : Ah;
        int k = (gt & 31) * 32 + aoff;
#pragma unroll
        for (int mt = 0; mt < 4; ++mt) {
          v8s a = *(const v8s*)(Ab + (long)(mt * 16 + colc) * kH + k);
          acc[0][mt] = __builtin_amdgcn_mfma_f32_16x16x32_bf16(a, w1[0][i], acc[0][mt], 0, 0, 0);
          acc[1][mt] = __builtin_amdgcn_mfma_f32_16x16x32_bf16(a, w1[1][i], acc[1][mt], 0, 0, 0);
        }
      }
      epilogue(1, acc, hNew + (long)kB * kH);
    }
    grid.sync();

    // ===== layer 2 =====
    {
      f32x4 acc[2][4] = {z4, z4, z4, z4, z4, z4, z4, z4};
      const u16* Ax = hNew + (long)kB * kH;
      const u16* Ah = hOld + 2L * kB * kH;
#pragma unroll
      for (int i = 0; i < 8; ++i) {
        int gt = w * 8 + i;
        const u16* Ab = (gt < 32) ? Ax : Ah;
        int k = (gt & 31) * 32 + aoff;
#pragma unroll
        for (int mt = 0; mt < 4; ++mt) {
          v8s a = *(const v8s*)(Ab + (long)(mt * 16 + colc) * kH + k);
          acc[0][mt] = __builtin_amdgcn_mfma_f32_16x16x32_bf16(a, w2[0][i], acc[0][mt], 0, 0, 0);
          acc[1][mt] = __builtin_amdgcn_mfma_f32_16x16x32_bf16(a, w2[1][i], acc[1][mt], 0, 0, 0);
        }
      }
      epilogue(2, acc, hNew + 2L * kB * kH);
    }
    grid.sync();

    // ===== FC feedback (generation phase only) — round-2-proven code =====
    if (t >= P - 1) {
      if (bid < 8 && w < 4) {  // n-tile = bid; wave = m-tile; full K per wave
        f32x4 u0 = z4, u1 = z4;
        const u16* ap = hNew + 2L * kB * kH + (long)(w * 16 + colc) * kH + aoff;
        const u16* bp = p.wbfc + (long)(bid * 16 + colc) * kH + aoff;
#pragma unroll
        for (int i = 0; i < 16; ++i) {
          v8s a0 = *(const v8s*)(ap + i * 32);
          v8s b0 = *(const v8s*)(bp + i * 32);
          v8s a1 = *(const v8s*)(ap + 512 + i * 32);
          v8s b1 = *(const v8s*)(bp + 512 + i * 32);
          u0 = __builtin_amdgcn_mfma_f32_16x16x32_bf16(a0, b0, u0, 0, 0, 0);
          u1 = __builtin_amdgcn_mfma_f32_16x16x32_bf16(a1, b1, u1, 0, 0, 0);
        }
        float bv = p.bfcs[bid * 16 + colc];
#pragma unroll
        for (int r = 0; r < 4; ++r) {
          float val = sigm(u0[r] + u1[r] + bv);
          int bb = w * 16 + kq * 4 + r, d = bid * 16 + colc;
          p.out[(long)(t + 1) * (kB * kD) + (long)bb * kD + d] = val;
          p.curx[(long)bb * kD + d] = f2b(val);
        }
      }
      grid.sync();
    }
  }
}

extern "C" void kernel_launch(void* const* d_in, const int* in_sizes, int n_in,
                              void* d_out, int out_size, void* d_ws, size_t ws_size,
                              hipStream_t stream) {
  Params p;
  p.x   = (const float*)d_in[0];
  p.h0  = (const float*)d_in[1];
  p.c0  = (const float*)d_in[2];
  p.Wi0 = (const float*)d_in[3];
  p.Wh0 = (const float*)d_in[4];
  p.bi0 = (const float*)d_in[5];
  p.bh0 = (const float*)d_in[6];
  p.Wi1 = (const float*)d_in[7];
  p.Wh1 = (const float*)d_in[8];
  p.bi1 = (const float*)d_in[9];
  p.bh1 = (const float*)d_in[10];
  p.Wi2 = (const float*)d_in[11];
  p.Wh2 = (const float*)d_in[12];
  p.bi2 = (const float*)d_in[13];
  p.bh2 = (const float*)d_in[14];
  p.Wfc = (const float*)d_in[15];
  p.bfc = (const float*)d_in[16];
  p.out = (float*)d_out;
  p.P = in_sizes[0] / (kB * kD);
  p.T = out_size / (kB * kD);

  char* w = (char*)d_ws;
  auto alloc = [&](size_t bytes) {
    char* r = w;
    w += (bytes + 255) & ~(size_t)255;
    return r;
  };
  p.wb0i = (u16*)alloc(4096L * kD * 2);
  p.wb0h = (u16*)alloc(4096L * kH * 2);
  p.wb1i = (u16*)alloc(4096L * kH * 2);
  p.wb1h = (u16*)alloc(4096L * kH * 2);
  p.wb2i = (u16*)alloc(4096L * kH * 2);
  p.wb2h = (u16*)alloc(4096L * kH * 2);
  p.wbfc = (u16*)alloc((long)kD * kH * 2);
  p.xb   = (u16*)alloc((long)p.P * kB * kD * 2);
  p.hA   = (u16*)alloc((long)kL * kB * kH * 2);
  p.hB   = (u16*)alloc((long)kL * kB * kH * 2);
  p.curx = (u16*)alloc((long)kB * kD * 2);
  p.b0   = (float*)alloc(4096 * 4);
  p.b1   = (float*)alloc(4096 * 4);
  p.b2   = (float*)alloc(4096 * 4);
  p.bfcs = (float*)alloc(kD * 4);

  hipLaunchKernelGGL(init_kernel, dim3(512), dim3(256), 0, stream, p);
  void* args[] = { &p };
  hipLaunchCooperativeKernel((const void*)rnn_kernel, dim3(NBLK), dim3(NTHR),
                             args, 0, stream);
}

// Round 6
// 36629.303 us; speedup vs baseline: 1.7416x; 1.3051x over previous
//
#include <hip/hip_runtime.h>

typedef short v8s __attribute__((ext_vector_type(8)));
typedef float f32x4 __attribute__((ext_vector_type(4)));
typedef unsigned short u16;

static constexpr int kB = 64;    // batch
static constexpr int kH = 1024;  // hidden
static constexpr int kD = 128;   // input dim
static constexpr int kL = 3;     // layers
static constexpr int NBLK = 128; // proven cooperative grid size
static constexpr int NTHR = 512; // 8 waves -> 8-way K-split

__device__ __forceinline__ u16 f2b(float f) {
  union { float f; unsigned u; } v; v.f = f;
  unsigned r = v.u + 0x7fffu + ((v.u >> 16) & 1u);
  return (u16)(r >> 16);
}

__device__ __forceinline__ float sigm(float x) { return 1.f / (1.f + expf(-x)); }

// Write-through stores: land at LLC (coherent point), leave no dirty L2 lines.
__device__ __forceinline__ void st16(u16* p, u16 v) {
  unsigned d = v;
  asm volatile("global_store_short %0, %1, off sc0 sc1" :: "v"(p), "v"(d) : "memory");
}
__device__ __forceinline__ void st32(float* p, float v) {
  asm volatile("global_store_dword %0, %1, off sc0 sc1" :: "v"(p), "v"(v) : "memory");
}

struct Params {
  const float *x, *h0, *c0;
  const float *Wi0, *Wh0, *bi0, *bh0;
  const float *Wi1, *Wh1, *bi1, *bh1;
  const float *Wi2, *Wh2, *bi2, *bh2;
  const float *Wfc, *bfc;
  float *out;
  u16 *wb0i, *wb0h, *wb1i, *wb1h, *wb2i, *wb2h, *wbfc;
  u16 *xb, *hA, *hB, *curx;
  float *b0, *b1, *b2, *bfcs;
  unsigned *bflags;  // [0]=arrive counter, [64]=generation (256 B apart)
  int P, T;
};

// Lightweight grid barrier. Pre: callers' communicated stores are sc0/sc1
// write-through. s_waitcnt vmcnt(0) drains them to LLC; relaxed LLC atomics
// rendezvous; per-thread ACQUIRE load afterwards emits buffer_inv (stale-L2
// kill) ordered before subsequent loads.
__device__ __forceinline__ void gbar(unsigned* cnt, unsigned* gen, unsigned& g) {
  asm volatile("s_waitcnt vmcnt(0)" ::: "memory");
  __syncthreads();
  if (threadIdx.x == 0) {
    if (__hip_atomic_fetch_add(cnt, 1u, __ATOMIC_RELAXED, __HIP_MEMORY_SCOPE_AGENT) == NBLK - 1u) {
      __hip_atomic_store(cnt, 0u, __ATOMIC_RELAXED, __HIP_MEMORY_SCOPE_AGENT);
      asm volatile("s_waitcnt vmcnt(0)" ::: "memory");  // cnt reset durable first
      __hip_atomic_store(gen, g + 1u, __ATOMIC_RELAXED, __HIP_MEMORY_SCOPE_AGENT);
    } else {
      while (__hip_atomic_load(gen, __ATOMIC_RELAXED, __HIP_MEMORY_SCOPE_AGENT) == g) {
        __builtin_amdgcn_s_sleep(2);
      }
    }
  }
  __syncthreads();
  (void)__hip_atomic_load(gen, __ATOMIC_ACQUIRE, __HIP_MEMORY_SCOPE_AGENT);
  g += 1u;
}

// ---------------- init: fp32 -> bf16 conversions, bias sums, state init ----
__global__ void init_kernel(Params p) {
  long gid = (long)blockIdx.x * blockDim.x + threadIdx.x;
  long stride = (long)gridDim.x * blockDim.x;
  const long nw0i = 4096L * kD, nwh = 4096L * kH, nfc = (long)kD * kH;
  for (long i = gid; i < nw0i; i += stride) p.wb0i[i] = f2b(p.Wi0[i]);
  for (long i = gid; i < nwh; i += stride) {
    p.wb0h[i] = f2b(p.Wh0[i]);
    p.wb1i[i] = f2b(p.Wi1[i]);
    p.wb1h[i] = f2b(p.Wh1[i]);
    p.wb2i[i] = f2b(p.Wi2[i]);
    p.wb2h[i] = f2b(p.Wh2[i]);
  }
  for (long i = gid; i < nfc; i += stride) p.wbfc[i] = f2b(p.Wfc[i]);
  for (long i = gid; i < 4096; i += stride) {
    p.b0[i] = p.bi0[i] + p.bh0[i];
    p.b1[i] = p.bi1[i] + p.bh1[i];
    p.b2[i] = p.bi2[i] + p.bh2[i];
  }
  for (long i = gid; i < kD; i += stride) p.bfcs[i] = p.bfc[i];
  for (long i = gid; i < 128; i += stride) p.bflags[i] = 0u;  // barrier state
  long nx = (long)p.P * kB * kD;
  for (long i = gid; i < nx; i += stride) {
    p.xb[i] = f2b(p.x[i]);
    p.out[i] = p.x[i];  // teacher-forced rows are exact copies
  }
  long nh = (long)kL * kB * kH;
  for (long i = gid; i < nh; i += stride) p.hA[i] = f2b(p.h0[i]);
}

// ---------------- persistent RNN: weights live in VGPRs, 8-way K-split ----
// 128 blocks x 512 thr. Block owns 8 hidden units [8b,8b+8) x 4 gates = 32
// gate-rows/layer as TWO n-tiles: tile j = gates {2j,2j+1}; col c -> gate
// 2j+(c>>3), unit c&7. Wave w (0..7) owns 1/8 of K; partials sum via LDS.
// MFMA 16x16x32: A row=lane&15(m), k=(lane>>4)*8+j; D col=lane&15, row=kq*4+r.
__global__ void __launch_bounds__(NTHR) rnn_kernel(Params p) {
  const int tid = threadIdx.x, bid = blockIdx.x;
  const int lane = tid & 63, w = tid >> 6;  // 8 waves
  const int colc = lane & 15, kq = lane >> 4;
  const int aoff = kq * 8;
  const int u7 = colc & 7, gh = colc >> 3;
  const long wr0 = (long)gh * kH + bid * 8 + u7;        // gate-rows 0/1 tile
  const long wr1 = (long)(2 + gh) * kH + bid * 8 + u7;  // gate-rows 2/3 tile
  unsigned* bcnt = p.bflags;
  unsigned* bgen = p.bflags + 64;
  unsigned bg = 0;

  // ---- one-time weight preload: 42 tiles = 168 VGPRs/wave ----
  const int cnt0 = (w < 4) ? 5 : 4;
  const int off0 = (w < 4) ? w * 5 : 20 + (w - 4) * 4;
  v8s w0[2][5], w1[2][8], w2[2][8];
#pragma unroll
  for (int i = 0; i < 5; ++i)
    if (i < cnt0) {
      int gt = off0 + i;
      if (gt < 4) {
        w0[0][i] = *(const v8s*)(p.wb0i + wr0 * kD + gt * 32 + aoff);
        w0[1][i] = *(const v8s*)(p.wb0i + wr1 * kD + gt * 32 + aoff);
      } else {
        w0[0][i] = *(const v8s*)(p.wb0h + wr0 * kH + (gt - 4) * 32 + aoff);
        w0[1][i] = *(const v8s*)(p.wb0h + wr1 * kH + (gt - 4) * 32 + aoff);
      }
    }
#pragma unroll
  for (int i = 0; i < 8; ++i) {
    int gt = w * 8 + i;
    const u16* s1 = (gt < 32) ? p.wb1i : p.wb1h;
    const u16* s2 = (gt < 32) ? p.wb2i : p.wb2h;
    int k = (gt & 31) * 32 + aoff;
    w1[0][i] = *(const v8s*)(s1 + wr0 * kH + k);
    w1[1][i] = *(const v8s*)(s1 + wr1 * kH + k);
    w2[0][i] = *(const v8s*)(s2 + wr0 * kH + k);
    w2[1][i] = *(const v8s*)(s2 + wr1 * kH + k);
  }

  // ---- per-thread cell state: 1 (batch, unit) cell per layer ----
  const int em = tid >> 3, eu = tid & 7;
  const int ehid = bid * 8 + eu;
  float cst[kL], brg[kL][4];
#pragma unroll
  for (int l = 0; l < kL; ++l)
    cst[l] = p.c0[(long)l * kB * kH + (long)em * kH + ehid];
  {
    const float* bp[3] = {p.b0, p.b1, p.b2};
#pragma unroll
    for (int l = 0; l < 3; ++l)
#pragma unroll
      for (int gg = 0; gg < 4; ++gg) brg[l][gg] = bp[l][gg * kH + ehid];
  }

  __shared__ float lg[8][64][18];  // stride 18: <=2-way bank aliasing
  const int T = p.T, P = p.P;
  const f32x4 z4 = {0.f, 0.f, 0.f, 0.f};

  auto epilogue = [&](int l, f32x4(&acc)[2][4], u16* hOut) {
    float pre[4];
#pragma unroll
    for (int mt = 0; mt < 4; ++mt)
#pragma unroll
      for (int r = 0; r < 4; ++r) lg[w][mt * 16 + kq * 4 + r][colc] = acc[0][mt][r];
    __syncthreads();
    {
      float s0 = 0.f, s1 = 0.f;
#pragma unroll
      for (int ww = 0; ww < 8; ++ww) {
        s0 += lg[ww][em][eu];
        s1 += lg[ww][em][8 + eu];
      }
      pre[0] = s0;
      pre[1] = s1;
    }
    __syncthreads();
#pragma unroll
    for (int mt = 0; mt < 4; ++mt)
#pragma unroll
      for (int r = 0; r < 4; ++r) lg[w][mt * 16 + kq * 4 + r][colc] = acc[1][mt][r];
    __syncthreads();
    {
      float s0 = 0.f, s1 = 0.f;
#pragma unroll
      for (int ww = 0; ww < 8; ++ww) {
        s0 += lg[ww][em][eu];
        s1 += lg[ww][em][8 + eu];
      }
      pre[2] = s0;
      pre[3] = s1;
    }
    float iv = pre[0] + brg[l][0], fv = pre[1] + brg[l][1];
    float gv = pre[2] + brg[l][2], ov = pre[3] + brg[l][3];
    float cn = sigm(fv) * cst[l] + sigm(iv) * tanhf(gv);
    cst[l] = cn;
    st16(hOut + (long)em * kH + ehid, f2b(sigm(ov) * tanhf(cn)));
  };

  for (int t = 0; t < T - 1; ++t) {
    const u16* hOld = (t & 1) ? p.hB : p.hA;
    u16* hNew = (t & 1) ? p.hA : p.hB;
    const u16* xin = (t < P) ? (p.xb + (long)t * kB * kD) : p.curx;

    // ===== layer 0 =====
    {
      f32x4 acc[2][4] = {z4, z4, z4, z4, z4, z4, z4, z4};
#pragma unroll
      for (int i = 0; i < 5; ++i)
        if (i < cnt0) {
          int gt = off0 + i;
          const u16* Ab;
          int stride, k;
          if (gt < 4) { Ab = xin;  stride = kD; k = gt * 32 + aoff; }
          else        { Ab = hOld; stride = kH; k = (gt - 4) * 32 + aoff; }
#pragma unroll
          for (int mt = 0; mt < 4; ++mt) {
            v8s a = *(const v8s*)(Ab + (long)(mt * 16 + colc) * stride + k);
            acc[0][mt] = __builtin_amdgcn_mfma_f32_16x16x32_bf16(a, w0[0][i], acc[0][mt], 0, 0, 0);
            acc[1][mt] = __builtin_amdgcn_mfma_f32_16x16x32_bf16(a, w0[1][i], acc[1][mt], 0, 0, 0);
          }
        }
      epilogue(0, acc, hNew);
    }
    gbar(bcnt, bgen, bg);

    // ===== layer 1 (x-part = h_l0 new, h-part = h_l1 old) =====
    {
      f32x4 acc[2][4] = {z4, z4, z4, z4, z4, z4, z4, z4};
      const u16* Ax = hNew;
      const u16* Ah = hOld + (long)kB * kH;
#pragma unroll
      for (int i = 0; i < 8; ++i) {
        int gt = w * 8 + i;
        const u16* Ab = (gt < 32) ? Ax : Ah;
        int k = (gt & 31) * 32 + aoff;
#pragma unroll
        for (int mt = 0; mt < 4; ++mt) {
          v8s a = *(const v8s*)(Ab + (long)(mt * 16 + colc) * kH + k);
          acc[0][mt] = __builtin_amdgcn_mfma_f32_16x16x32_bf16(a, w1[0][i], acc[0][mt], 0, 0, 0);
          acc[1][mt] = __builtin_amdgcn_mfma_f32_16x16x32_bf16(a, w1[1][i], acc[1][mt], 0, 0, 0);
        }
      }
      epilogue(1, acc, hNew + (long)kB * kH);
    }
    gbar(bcnt, bgen, bg);

    // ===== layer 2 =====
    {
      f32x4 acc[2][4] = {z4, z4, z4, z4, z4, z4, z4, z4};
      const u16* Ax = hNew + (long)kB * kH;
      const u16* Ah = hOld + 2L * kB * kH;
#pragma unroll
      for (int i = 0; i < 8; ++i) {
        int gt = w * 8 + i;
        const u16* Ab = (gt < 32) ? Ax : Ah;
        int k = (gt & 31) * 32 + aoff;
#pragma unroll
        for (int mt = 0; mt < 4; ++mt) {
          v8s a = *(const v8s*)(Ab + (long)(mt * 16 + colc) * kH + k);
          acc[0][mt] = __builtin_amdgcn_mfma_f32_16x16x32_bf16(a, w2[0][i], acc[0][mt], 0, 0, 0);
          acc[1][mt] = __builtin_amdgcn_mfma_f32_16x16x32_bf16(a, w2[1][i], acc[1][mt], 0, 0, 0);
        }
      }
      epilogue(2, acc, hNew + 2L * kB * kH);
    }
    gbar(bcnt, bgen, bg);

    // ===== FC feedback (generation phase only) =====
    if (t >= P - 1) {
      if (bid < 8 && w < 4) {  // n-tile = bid; wave = m-tile; full K per wave
        f32x4 u0 = z4, u1 = z4;
        const u16* ap = hNew + 2L * kB * kH + (long)(w * 16 + colc) * kH + aoff;
        const u16* bp = p.wbfc + (long)(bid * 16 + colc) * kH + aoff;
#pragma unroll
        for (int i = 0; i < 16; ++i) {
          v8s a0 = *(const v8s*)(ap + i * 32);
          v8s b0 = *(const v8s*)(bp + i * 32);
          v8s a1 = *(const v8s*)(ap + 512 + i * 32);
          v8s b1 = *(const v8s*)(bp + 512 + i * 32);
          u0 = __builtin_amdgcn_mfma_f32_16x16x32_bf16(a0, b0, u0, 0, 0, 0);
          u1 = __builtin_amdgcn_mfma_f32_16x16x32_bf16(a1, b1, u1, 0, 0, 0);
        }
        float bv = p.bfcs[bid * 16 + colc];
#pragma unroll
        for (int r = 0; r < 4; ++r) {
          float val = sigm(u0[r] + u1[r] + bv);
          int bb = w * 16 + kq * 4 + r, d = bid * 16 + colc;
          st32(p.out + (long)(t + 1) * (kB * kD) + (long)bb * kD + d, val);
          st16(p.curx + (long)bb * kD + d, f2b(val));
        }
      }
      gbar(bcnt, bgen, bg);
    }
  }
}

extern "C" void kernel_launch(void* const* d_in, const int* in_sizes, int n_in,
                              void* d_out, int out_size, void* d_ws, size_t ws_size,
                              hipStream_t stream) {
  Params p;
  p.x   = (const float*)d_in[0];
  p.h0  = (const float*)d_in[1];
  p.c0  = (const float*)d_in[2];
  p.Wi0 = (const float*)d_in[3];
  p.Wh0 = (const float*)d_in[4];
  p.bi0 = (const float*)d_in[5];
  p.bh0 = (const float*)d_in[6];
  p.Wi1 = (const float*)d_in[7];
  p.Wh1 = (const float*)d_in[8];
  p.bi1 = (const float*)d_in[9];
  p.bh1 = (const float*)d_in[10];
  p.Wi2 = (const float*)d_in[11];
  p.Wh2 = (const float*)d_in[12];
  p.bi2 = (const float*)d_in[13];
  p.bh2 = (const float*)d_in[14];
  p.Wfc = (const float*)d_in[15];
  p.bfc = (const float*)d_in[16];
  p.out = (float*)d_out;
  p.P = in_sizes[0] / (kB * kD);
  p.T = out_size / (kB * kD);

  char* w = (char*)d_ws;
  auto alloc = [&](size_t bytes) {
    char* r = w;
    w += (bytes + 255) & ~(size_t)255;
    return r;
  };
  p.wb0i = (u16*)alloc(4096L * kD * 2);
  p.wb0h = (u16*)alloc(4096L * kH * 2);
  p.wb1i = (u16*)alloc(4096L * kH * 2);
  p.wb1h = (u16*)alloc(4096L * kH * 2);
  p.wb2i = (u16*)alloc(4096L * kH * 2);
  p.wb2h = (u16*)alloc(4096L * kH * 2);
  p.wbfc = (u16*)alloc((long)kD * kH * 2);
  p.xb   = (u16*)alloc((long)p.P * kB * kD * 2);
  p.hA   = (u16*)alloc((long)kL * kB * kH * 2);
  p.hB   = (u16*)alloc((long)kL * kB * kH * 2);
  p.curx = (u16*)alloc((long)kB * kD * 2);
  p.b0   = (float*)alloc(4096 * 4);
  p.b1   = (float*)alloc(4096 * 4);
  p.b2   = (float*)alloc(4096 * 4);
  p.bfcs = (float*)alloc(kD * 4);
  p.bflags = (unsigned*)alloc(128 * 4);

  hipLaunchKernelGGL(init_kernel, dim3(512), dim3(256), 0, stream, p);
  void* args[] = { &p };
  hipLaunchCooperativeKernel((const void*)rnn_kernel, dim3(NBLK), dim3(NTHR),
                             args, 0, stream);
}

// Round 7
// 36559.897 us; speedup vs baseline: 1.7449x; 1.0019x over previous
//
#include <hip/hip_runtime.h>

typedef short v8s __attribute__((ext_vector_type(8)));
typedef float f32x4 __attribute__((ext_vector_type(4)));
typedef unsigned short u16;

static constexpr int kB = 64;    // batch
static constexpr int kH = 1024;  // hidden
static constexpr int kD = 128;   // input dim
static constexpr int kL = 3;     // layers
static constexpr int NBLK = 128; // proven cooperative grid size
static constexpr int NTHR = 512; // 8 waves -> 8-way K-split
static constexpr int NFLAG = 8192;  // barrier flag words (128 lines + gen)

__device__ __forceinline__ u16 f2b(float f) {
  union { float f; unsigned u; } v; v.f = f;
  unsigned r = v.u + 0x7fffu + ((v.u >> 16) & 1u);
  return (u16)(r >> 16);
}

__device__ __forceinline__ float sigm(float x) { return 1.f / (1.f + expf(-x)); }

// Write-through stores: land at LLC (coherent point), leave no dirty L2 lines.
__device__ __forceinline__ void st16(u16* p, u16 v) {
  unsigned d = v;
  asm volatile("global_store_short %0, %1, off sc0 sc1" :: "v"(p), "v"(d) : "memory");
}
__device__ __forceinline__ void st32(float* p, float v) {
  asm volatile("global_store_dword %0, %1, off sc0 sc1" :: "v"(p), "v"(v) : "memory");
}
__device__ __forceinline__ void st32u(unsigned* p, unsigned v) {
  asm volatile("global_store_dword %0, %1, off sc0 sc1" :: "v"(p), "v"(v) : "memory");
}

struct Params {
  const float *x, *h0, *c0;
  const float *Wi0, *Wh0, *bi0, *bh0;
  const float *Wi1, *Wh1, *bi1, *bh1;
  const float *Wi2, *Wh2, *bi2, *bh2;
  const float *Wfc, *bfc;
  float *out;
  u16 *wb0i, *wb0h, *wb1i, *wb1h, *wb2i, *wb2h, *wbfc;
  u16 *xb, *hA, *hB, *curx;
  float *b0, *b1, *b2, *bfcs;
  unsigned *bflags;  // flags[b*32] per-block lines; gen at [NBLK*32+32]
  int P, T;
};

// Serialization-free grid barrier (flag array + checker block).
// Arrival: per-wave vmcnt drain -> block syncthreads -> thread0 stores its
// own generation flag (own cache line, parallel across blocks, no RMW).
// Block 0: threads 0..127 poll the 128 flags in parallel; publish gen.
// Others: thread0 spins on gen. Exit: per-thread ACQUIRE load (buffer_inv)
// kills stale L1/L2 lines before the next layer's h-reads.
__device__ __forceinline__ void gbar(unsigned* flags, unsigned* gen,
                                     unsigned& g, int bid) {
  const unsigned tgt = g + 1u;
  asm volatile("s_waitcnt vmcnt(0)" ::: "memory");  // drain this wave's stores
  __syncthreads();                                  // all waves drained
  if (threadIdx.x == 0) st32u(flags + bid * 32, tgt);
  if (bid == 0) {
    const int i = threadIdx.x;
    unsigned* fp = flags + i * 32;
    for (;;) {
      unsigned v = (i < NBLK)
          ? __hip_atomic_load(fp, __ATOMIC_RELAXED, __HIP_MEMORY_SCOPE_AGENT)
          : tgt;
      if (__syncthreads_and((int)(v >= tgt))) break;
      __builtin_amdgcn_s_sleep(1);
    }
    if (threadIdx.x == 0)
      __hip_atomic_store(gen, tgt, __ATOMIC_RELAXED, __HIP_MEMORY_SCOPE_AGENT);
  } else {
    if (threadIdx.x == 0) {
      while (__hip_atomic_load(gen, __ATOMIC_RELAXED, __HIP_MEMORY_SCOPE_AGENT) < tgt)
        __builtin_amdgcn_s_sleep(2);
    }
    __syncthreads();
  }
  (void)__hip_atomic_load(gen, __ATOMIC_ACQUIRE, __HIP_MEMORY_SCOPE_AGENT);
  g = tgt;
}

// ---------------- init: fp32 -> bf16 conversions, bias sums, state init ----
__global__ void init_kernel(Params p) {
  long gid = (long)blockIdx.x * blockDim.x + threadIdx.x;
  long stride = (long)gridDim.x * blockDim.x;
  const long nw0i = 4096L * kD, nwh = 4096L * kH, nfc = (long)kD * kH;
  for (long i = gid; i < nw0i; i += stride) p.wb0i[i] = f2b(p.Wi0[i]);
  for (long i = gid; i < nwh; i += stride) {
    p.wb0h[i] = f2b(p.Wh0[i]);
    p.wb1i[i] = f2b(p.Wi1[i]);
    p.wb1h[i] = f2b(p.Wh1[i]);
    p.wb2i[i] = f2b(p.Wi2[i]);
    p.wb2h[i] = f2b(p.Wh2[i]);
  }
  for (long i = gid; i < nfc; i += stride) p.wbfc[i] = f2b(p.Wfc[i]);
  for (long i = gid; i < 4096; i += stride) {
    p.b0[i] = p.bi0[i] + p.bh0[i];
    p.b1[i] = p.bi1[i] + p.bh1[i];
    p.b2[i] = p.bi2[i] + p.bh2[i];
  }
  for (long i = gid; i < kD; i += stride) p.bfcs[i] = p.bfc[i];
  for (long i = gid; i < NFLAG; i += stride) p.bflags[i] = 0u;  // barrier state
  long nx = (long)p.P * kB * kD;
  for (long i = gid; i < nx; i += stride) {
    p.xb[i] = f2b(p.x[i]);
    p.out[i] = p.x[i];  // teacher-forced rows are exact copies
  }
  long nh = (long)kL * kB * kH;
  for (long i = gid; i < nh; i += stride) p.hA[i] = f2b(p.h0[i]);
}

// ---------------- persistent RNN: weights live in VGPRs, 8-way K-split ----
// 128 blocks x 512 thr. Block owns 8 hidden units [8b,8b+8) x 4 gates = 32
// gate-rows/layer as TWO n-tiles: tile j = gates {2j,2j+1}; col c -> gate
// 2j+(c>>3), unit c&7. Wave w (0..7) owns 1/8 of K; partials sum via LDS.
// MFMA 16x16x32: A row=lane&15(m), k=(lane>>4)*8+j; D col=lane&15, row=kq*4+r.
__global__ void __launch_bounds__(NTHR) rnn_kernel(Params p) {
  const int tid = threadIdx.x, bid = blockIdx.x;
  const int lane = tid & 63, w = tid >> 6;  // 8 waves
  const int colc = lane & 15, kq = lane >> 4;
  const int aoff = kq * 8;
  const int u7 = colc & 7, gh = colc >> 3;
  const long wr0 = (long)gh * kH + bid * 8 + u7;        // gate-rows 0/1 tile
  const long wr1 = (long)(2 + gh) * kH + bid * 8 + u7;  // gate-rows 2/3 tile
  unsigned* bgen = p.bflags + NBLK * 32 + 32;
  unsigned bg = 0;

  // ---- one-time weight preload: 42 tiles = 168 VGPRs/wave ----
  const int cnt0 = (w < 4) ? 5 : 4;
  const int off0 = (w < 4) ? w * 5 : 20 + (w - 4) * 4;
  v8s w0[2][5], w1[2][8], w2[2][8];
#pragma unroll
  for (int i = 0; i < 5; ++i)
    if (i < cnt0) {
      int gt = off0 + i;
      if (gt < 4) {
        w0[0][i] = *(const v8s*)(p.wb0i + wr0 * kD + gt * 32 + aoff);
        w0[1][i] = *(const v8s*)(p.wb0i + wr1 * kD + gt * 32 + aoff);
      } else {
        w0[0][i] = *(const v8s*)(p.wb0h + wr0 * kH + (gt - 4) * 32 + aoff);
        w0[1][i] = *(const v8s*)(p.wb0h + wr1 * kH + (gt - 4) * 32 + aoff);
      }
    }
#pragma unroll
  for (int i = 0; i < 8; ++i) {
    int gt = w * 8 + i;
    const u16* s1 = (gt < 32) ? p.wb1i : p.wb1h;
    const u16* s2 = (gt < 32) ? p.wb2i : p.wb2h;
    int k = (gt & 31) * 32 + aoff;
    w1[0][i] = *(const v8s*)(s1 + wr0 * kH + k);
    w1[1][i] = *(const v8s*)(s1 + wr1 * kH + k);
    w2[0][i] = *(const v8s*)(s2 + wr0 * kH + k);
    w2[1][i] = *(const v8s*)(s2 + wr1 * kH + k);
  }

  // ---- per-thread cell state: 1 (batch, unit) cell per layer ----
  const int em = tid >> 3, eu = tid & 7;
  const int ehid = bid * 8 + eu;
  float cst[kL], brg[kL][4];
#pragma unroll
  for (int l = 0; l < kL; ++l)
    cst[l] = p.c0[(long)l * kB * kH + (long)em * kH + ehid];
  {
    const float* bp[3] = {p.b0, p.b1, p.b2};
#pragma unroll
    for (int l = 0; l < 3; ++l)
#pragma unroll
      for (int gg = 0; gg < 4; ++gg) brg[l][gg] = bp[l][gg * kH + ehid];
  }

  __shared__ float lg[8][64][18];  // stride 18: <=2-way bank aliasing
  const int T = p.T, P = p.P;
  const f32x4 z4 = {0.f, 0.f, 0.f, 0.f};

  auto epilogue = [&](int l, f32x4(&acc)[2][4], u16* hOut) {
    float pre[4];
#pragma unroll
    for (int mt = 0; mt < 4; ++mt)
#pragma unroll
      for (int r = 0; r < 4; ++r) lg[w][mt * 16 + kq * 4 + r][colc] = acc[0][mt][r];
    __syncthreads();
    {
      float s0 = 0.f, s1 = 0.f;
#pragma unroll
      for (int ww = 0; ww < 8; ++ww) {
        s0 += lg[ww][em][eu];
        s1 += lg[ww][em][8 + eu];
      }
      pre[0] = s0;
      pre[1] = s1;
    }
    __syncthreads();
#pragma unroll
    for (int mt = 0; mt < 4; ++mt)
#pragma unroll
      for (int r = 0; r < 4; ++r) lg[w][mt * 16 + kq * 4 + r][colc] = acc[1][mt][r];
    __syncthreads();
    {
      float s0 = 0.f, s1 = 0.f;
#pragma unroll
      for (int ww = 0; ww < 8; ++ww) {
        s0 += lg[ww][em][eu];
        s1 += lg[ww][em][8 + eu];
      }
      pre[2] = s0;
      pre[3] = s1;
    }
    float iv = pre[0] + brg[l][0], fv = pre[1] + brg[l][1];
    float gv = pre[2] + brg[l][2], ov = pre[3] + brg[l][3];
    float cn = sigm(fv) * cst[l] + sigm(iv) * tanhf(gv);
    cst[l] = cn;
    st16(hOut + (long)em * kH + ehid, f2b(sigm(ov) * tanhf(cn)));
  };

  for (int t = 0; t < T - 1; ++t) {
    const u16* hOld = (t & 1) ? p.hB : p.hA;
    u16* hNew = (t & 1) ? p.hA : p.hB;
    const u16* xin = (t < P) ? (p.xb + (long)t * kB * kD) : p.curx;

    // ===== layer 0 =====
    {
      f32x4 acc[2][4] = {z4, z4, z4, z4, z4, z4, z4, z4};
#pragma unroll
      for (int i = 0; i < 5; ++i)
        if (i < cnt0) {
          int gt = off0 + i;
          const u16* Ab;
          int stride, k;
          if (gt < 4) { Ab = xin;  stride = kD; k = gt * 32 + aoff; }
          else        { Ab = hOld; stride = kH; k = (gt - 4) * 32 + aoff; }
#pragma unroll
          for (int mt = 0; mt < 4; ++mt) {
            v8s a = *(const v8s*)(Ab + (long)(mt * 16 + colc) * stride + k);
            acc[0][mt] = __builtin_amdgcn_mfma_f32_16x16x32_bf16(a, w0[0][i], acc[0][mt], 0, 0, 0);
            acc[1][mt] = __builtin_amdgcn_mfma_f32_16x16x32_bf16(a, w0[1][i], acc[1][mt], 0, 0, 0);
          }
        }
      epilogue(0, acc, hNew);
    }
    gbar(p.bflags, bgen, bg, bid);

    // ===== layer 1 (x-part = h_l0 new, h-part = h_l1 old) =====
    {
      f32x4 acc[2][4] = {z4, z4, z4, z4, z4, z4, z4, z4};
      const u16* Ax = hNew;
      const u16* Ah = hOld + (long)kB * kH;
#pragma unroll
      for (int i = 0; i < 8; ++i) {
        int gt = w * 8 + i;
        const u16* Ab = (gt < 32) ? Ax : Ah;
        int k = (gt & 31) * 32 + aoff;
#pragma unroll
        for (int mt = 0; mt < 4; ++mt) {
          v8s a = *(const v8s*)(Ab + (long)(mt * 16 + colc) * kH + k);
          acc[0][mt] = __builtin_amdgcn_mfma_f32_16x16x32_bf16(a, w1[0][i], acc[0][mt], 0, 0, 0);
          acc[1][mt] = __builtin_amdgcn_mfma_f32_16x16x32_bf16(a, w1[1][i], acc[1][mt], 0, 0, 0);
        }
      }
      epilogue(1, acc, hNew + (long)kB * kH);
    }
    gbar(p.bflags, bgen, bg, bid);

    // ===== layer 2 =====
    {
      f32x4 acc[2][4] = {z4, z4, z4, z4, z4, z4, z4, z4};
      const u16* Ax = hNew + (long)kB * kH;
      const u16* Ah = hOld + 2L * kB * kH;
#pragma unroll
      for (int i = 0; i < 8; ++i) {
        int gt = w * 8 + i;
        const u16* Ab = (gt < 32) ? Ax : Ah;
        int k = (gt & 31) * 32 + aoff;
#pragma unroll
        for (int mt = 0; mt < 4; ++mt) {
          v8s a = *(const v8s*)(Ab + (long)(mt * 16 + colc) * kH + k);
          acc[0][mt] = __builtin_amdgcn_mfma_f32_16x16x32_bf16(a, w2[0][i], acc[0][mt], 0, 0, 0);
          acc[1][mt] = __builtin_amdgcn_mfma_f32_16x16x32_bf16(a, w2[1][i], acc[1][mt], 0, 0, 0);
        }
      }
      epilogue(2, acc, hNew + 2L * kB * kH);
    }
    gbar(p.bflags, bgen, bg, bid);

    // ===== FC feedback (generation phase only) =====
    if (t >= P - 1) {
      if (bid < 8 && w < 4) {  // n-tile = bid; wave = m-tile; full K per wave
        f32x4 u0 = z4, u1 = z4;
        const u16* ap = hNew + 2L * kB * kH + (long)(w * 16 + colc) * kH + aoff;
        const u16* bp = p.wbfc + (long)(bid * 16 + colc) * kH + aoff;
#pragma unroll
        for (int i = 0; i < 16; ++i) {
          v8s a0 = *(const v8s*)(ap + i * 32);
          v8s b0 = *(const v8s*)(bp + i * 32);
          v8s a1 = *(const v8s*)(ap + 512 + i * 32);
          v8s b1 = *(const v8s*)(bp + 512 + i * 32);
          u0 = __builtin_amdgcn_mfma_f32_16x16x32_bf16(a0, b0, u0, 0, 0, 0);
          u1 = __builtin_amdgcn_mfma_f32_16x16x32_bf16(a1, b1, u1, 0, 0, 0);
        }
        float bv = p.bfcs[bid * 16 + colc];
#pragma unroll
        for (int r = 0; r < 4; ++r) {
          float val = sigm(u0[r] + u1[r] + bv);
          int bb = w * 16 + kq * 4 + r, d = bid * 16 + colc;
          st32(p.out + (long)(t + 1) * (kB * kD) + (long)bb * kD + d, val);
          st16(p.curx + (long)bb * kD + d, f2b(val));
        }
      }
      gbar(p.bflags, bgen, bg, bid);
    }
  }
}

extern "C" void kernel_launch(void* const* d_in, const int* in_sizes, int n_in,
                              void* d_out, int out_size, void* d_ws, size_t ws_size,
                              hipStream_t stream) {
  Params p;
  p.x   = (const float*)d_in[0];
  p.h0  = (const float*)d_in[1];
  p.c0  = (const float*)d_in[2];
  p.Wi0 = (const float*)d_in[3];
  p.Wh0 = (const float*)d_in[4];
  p.bi0 = (const float*)d_in[5];
  p.bh0 = (const float*)d_in[6];
  p.Wi1 = (const float*)d_in[7];
  p.Wh1 = (const float*)d_in[8];
  p.bi1 = (const float*)d_in[9];
  p.bh1 = (const float*)d_in[10];
  p.Wi2 = (const float*)d_in[11];
  p.Wh2 = (const float*)d_in[12];
  p.bi2 = (const float*)d_in[13];
  p.bh2 = (const float*)d_in[14];
  p.Wfc = (const float*)d_in[15];
  p.bfc = (const float*)d_in[16];
  p.out = (float*)d_out;
  p.P = in_sizes[0] / (kB * kD);
  p.T = out_size / (kB * kD);

  char* w = (char*)d_ws;
  auto alloc = [&](size_t bytes) {
    char* r = w;
    w += (bytes + 255) & ~(size_t)255;
    return r;
  };
  p.wb0i = (u16*)alloc(4096L * kD * 2);
  p.wb0h = (u16*)alloc(4096L * kH * 2);
  p.wb1i = (u16*)alloc(4096L * kH * 2);
  p.wb1h = (u16*)alloc(4096L * kH * 2);
  p.wb2i = (u16*)alloc(4096L * kH * 2);
  p.wb2h = (u16*)alloc(4096L * kH * 2);
  p.wbfc = (u16*)alloc((long)kD * kH * 2);
  p.xb   = (u16*)alloc((long)p.P * kB * kD * 2);
  p.hA   = (u16*)alloc((long)kL * kB * kH * 2);
  p.hB   = (u16*)alloc((long)kL * kB * kH * 2);
  p.curx = (u16*)alloc((long)kB * kD * 2);
  p.b0   = (float*)alloc(4096 * 4);
  p.b1   = (float*)alloc(4096 * 4);
  p.b2   = (float*)alloc(4096 * 4);
  p.bfcs = (float*)alloc(kD * 4);
  p.bflags = (unsigned*)alloc(NFLAG * 4);

  hipLaunchKernelGGL(init_kernel, dim3(512), dim3(256), 0, stream, p);
  void* args[] = { &p };
  hipLaunchCooperativeKernel((const void*)rnn_kernel, dim3(NBLK), dim3(NTHR),
                             args, 0, stream);
}